// Round 8
// baseline (113.952 us; speedup 1.0000x reference)
//
#include <hip/hip_runtime.h>
#include <math.h>

#define HH 256
#define WW 256
#define NG 714
#define NROWS 768          // padded to 3x256 prep grid; pad rows always culled
#define NGP4 716           // s_tz padded for float4 rank loop
#define RPW 192            // rows per wave (4 waves x 192 = 768 = NROWS exactly)
#define FOCALF 128.0f
#define EPS2D_F 0.3f
#define ALPHA_MIN_F (1.0f/255.0f)
#define CAM_T_F 8.0f
#define LOG2E_F 1.4426950408889634f
#define PR 12              // floats/row: [mx,my,A2n,B2n][C2n,K,cr,cg][cb,e,f,thr]
#define T_EPS 0.003f       // in-wave early-break bound (error <= eps per channel)

// Kernel 1: projection + conic + stable depth rank + scatter into sorted rows.
// Conic stored NEGATED, prefolded with log2(e); K = log2(op) folded additively:
// sg = A2n*dx^2 + B2n*dx*dy + C2n*dy^2 + K  ->  alpha = exp2(sg) = op*exp(-sigma).
// Cull fields: e = C-B^2/4A, f = A-B^2/4C (positive conic, >=0);
// gaussian irrelevant for a box iff max(e*dymin^2, f*dxmin^2) > thr = log2(255)+K
// (then alpha < 1/255 for EVERY pixel in the box -> reference zeroes it: EXACT cull).
__global__ __launch_bounds__(256) void gs_prep(
    const float* __restrict__ means, const float* __restrict__ quats,
    const float* __restrict__ scales, const float* __restrict__ opacities,
    const float* __restrict__ rgbs, float* __restrict__ params)
{
    __shared__ float s_tz[NGP4];
    const int lane = threadIdx.x;
    const int i = blockIdx.x * 256 + lane;

    for (int j = lane; j < NGP4; j += 256)
        s_tz[j] = (j < NG) ? (means[3*j+2] + CAM_T_F) : INFINITY;
    __syncthreads();

    if (i >= NROWS) return;
    if (i >= NG) {                      // pad rows: always culled (0 > thr=-1)
        float4* row = (float4*)(params + i*PR);
        row[0] = make_float4(0.f,0.f,0.f,0.f);
        row[1] = make_float4(0.f,0.f,0.f,0.f);
        row[2] = make_float4(0.f,0.f,0.f,-1.f);
        return;
    }

    float m0 = means[i*3+0], m1 = means[i*3+1];
    float tz = s_tz[i];
    float qw = quats[i*4+0], qx = quats[i*4+1], qy = quats[i*4+2], qz = quats[i*4+3];
    float qn = rsqrtf(qw*qw + qx*qx + qy*qy + qz*qz);
    qw*=qn; qx*=qn; qy*=qn; qz*=qn;
    float sx = scales[i*3+0], sy = scales[i*3+1], sz = scales[i*3+2];
    float s0 = sx*sx, s1 = sy*sy, s2 = sz*sz;
    float R00 = 1.f-2.f*(qy*qy+qz*qz), R01 = 2.f*(qx*qy-qw*qz), R02 = 2.f*(qx*qz+qw*qy);
    float R10 = 2.f*(qx*qy+qw*qz),     R11 = 1.f-2.f*(qx*qx+qz*qz), R12 = 2.f*(qy*qz-qw*qx);
    float R20 = 2.f*(qx*qz-qw*qy),     R21 = 2.f*(qy*qz+qw*qx),     R22 = 1.f-2.f*(qx*qx+qy*qy);
    float S00 = R00*R00*s0 + R01*R01*s1 + R02*R02*s2;
    float S01 = R00*R10*s0 + R01*R11*s1 + R02*R12*s2;
    float S02 = R00*R20*s0 + R01*R21*s1 + R02*R22*s2;
    float S11 = R10*R10*s0 + R11*R11*s1 + R12*R12*s2;
    float S12 = R10*R20*s0 + R11*R21*s1 + R12*R22*s2;
    float S22 = R20*R20*s0 + R21*R21*s1 + R22*R22*s2;
    float inv = 1.f/tz;
    float mx = FOCALF*m0*inv + 0.5f*WW;
    float my = FOCALF*m1*inv + 0.5f*HH;
    float j0 = FOCALF*inv;
    float j2 = -FOCALF*m0*inv*inv;
    float j5 = -FOCALF*m1*inv*inv;
    float a = j0*j0*S00 + 2.f*j0*j2*S02 + j2*j2*S22 + EPS2D_F;
    float b = j0*(j0*S01 + j2*S12) + j5*(j0*S02 + j2*S22);
    float c = j0*j0*S11 + 2.f*j0*j5*S12 + j5*j5*S22 + EPS2D_F;
    float det = a*c - b*b;
    float idet = 1.f/det;
    float hA = 0.5f*c*idet*LOG2E_F;      // positive conic terms (log2-scaled)
    float Bc = -b*idet*LOG2E_F;
    float hC = 0.5f*a*idet*LOG2E_F;
    float e  = hC - Bc*Bc/(4.f*hA);      // min over dx of sigma' = e*dy^2
    float f  = hA - Bc*Bc/(4.f*hC);      // min over dy of sigma' = f*dx^2
    float op = 1.f/(1.f+__expf(-opacities[i]));
    float K  = log2f(op);                // folded into exponent
    float thr = log2f(255.f) + K;        // cull iff bound > thr
    float cr = 1.f/(1.f+__expf(-rgbs[i*3+0]));
    float cg = 1.f/(1.f+__expf(-rgbs[i*3+1]));
    float cb = 1.f/(1.f+__expf(-rgbs[i*3+2]));

    const float4* t4 = (const float4*)s_tz;
    int rank = 0;
    #pragma unroll 4
    for (int jj = 0; jj < NGP4/4; ++jj) {
        float4 v = t4[jj];
        int j = 4*jj;
        rank += (v.x < tz) || (v.x == tz && (j+0) < i);
        rank += (v.y < tz) || (v.y == tz && (j+1) < i);
        rank += (v.z < tz) || (v.z == tz && (j+2) < i);
        rank += (v.w < tz) || (v.w == tz && (j+3) < i);
    }

    float4* row = (float4*)(params + rank*PR);
    row[0] = make_float4(mx, my, -hA, -Bc);
    row[1] = make_float4(-hC, K, cr, cg);
    row[2] = make_float4(cb, e, f, thr);
}

// Kernel 2 (final): full-depth compositing per 8x8 tile, in-block 4-way fold.
// 1024 blocks = 1024 tiles (8x8 px), 4/CU avg (many small blocks -- round-3/6
// lesson). Block = 4 waves = 4 depth quarters (192 sorted rows each); lane =
// ONE pixel. Per wave: ballot pre-pass in 3 rounds of 64 (lanes cull-test one
// row each -> 3x64-bit hit mask; round-5 win: no scan stalls), then hit-only
// loop via 3-word __ffsll iterator with distance-2 register pipeline;
// register-only ballot early break (bounded error < T_EPS). One narrow
// __syncthreads (4 waves), wave 0 folds the 4 depth partials in order and
// writes out directly. Two dispatches total: no combine kernel, no qpart
// round-trip, no flags, no fences (round-1 lesson). Trade accepted: ~2.5x
// more (tile,gaussian) cull pairs at ~25 VALU/hit-lane vs 55 (no 4-row
// amortization) -- structure savings (~4-5us) should win.
__global__ __launch_bounds__(256) void gs_composite(
    const float* __restrict__ params, float* __restrict__ out)
{
    __shared__ float4 part[4][64];          // [wave][pixel] = 4 KB
    const int tx = threadIdx.x;             // 0..63 = pixel in tile
    const int wv = __builtin_amdgcn_readfirstlane((int)threadIdx.y);  // 0..3
    const int tile = blockIdx.x;
    const int x0 = (tile & 31) * 8;
    const int y0 = (tile >> 5) * 8;
    const float px = (float)(x0 + (tx & 7)) + 0.5f;
    const float py = (float)(y0 + (tx >> 3)) + 0.5f;
    const float xc   = (float)x0 + 4.0f;    // box center, half-span 3.5
    const float ycen = (float)y0 + 4.0f;
    const int n0 = wv * RPW;                // wave's depth quarter start

    const float4* p4 = (const float4*)params;

    // Pre-pass: 3 ballot rounds; lane l tests rows n0+l, n0+64+l, n0+128+l.
    unsigned long long m0, m1, m2;
    #pragma unroll
    for (int rnd = 0; rnd < 3; ++rnd) {
        const int r = n0 + (rnd << 6) + tx;     // < 768 always
        float4 q0 = p4[3*r];
        float4 q2 = p4[3*r+2];
        float dymin = fmaxf(fabsf(ycen - q0.y) - 3.5f, 0.f);
        float dxmin = fmaxf(fabsf(xc   - q0.x) - 3.5f, 0.f);
        float mm = fmaxf(q2.y*dymin*dymin, q2.z*dxmin*dxmin);
        bool h = !(mm > q2.w);                  // exact cull; pads: 0 > -1
        unsigned long long bm = __ballot(h);
        if (rnd == 0) m0 = bm; else if (rnd == 1) m1 = bm; else m2 = bm;
    }

    // Depth-ordered next-hit iterator over the 3-word mask.
    #define NEXT_ROW(dst) {                                             \
        dst = -1;                                                       \
        if (m0)      { dst = n0       + (__ffsll(m0)-1); m0 &= m0-1; }  \
        else if (m1) { dst = n0 + 64  + (__ffsll(m1)-1); m1 &= m1-1; }  \
        else if (m2) { dst = n0 + 128 + (__ffsll(m2)-1); m2 &= m2-1; }  \
    }

    float T = 1.f, cr = 0.f, cg = 0.f, cb = 0.f;

    int ra, rb;
    float4 A0,A1,A2,B0,B1,B2;
    NEXT_ROW(ra);
    if (ra >= 0) { A0=p4[3*ra]; A1=p4[3*ra+1]; A2=p4[3*ra+2]; }
    NEXT_ROW(rb);
    if (rb >= 0) { B0=p4[3*rb]; B1=p4[3*rb+1]; B2=p4[3*rb+2]; }
    while (ra >= 0) {
        int rc; NEXT_ROW(rc);
        float4 C0,C1,C2;
        if (rc >= 0) { C0=p4[3*rc]; C1=p4[3*rc+1]; C2=p4[3*rc+2]; }

        float dy = py - A0.y;
        float dx = px - A0.x;
        float axx = fmaf(A0.z*dx, dx, A1.y);    // A2n*dx^2 + K
        float sg  = fmaf(A0.w*dx, dy, fmaf(A1.x*dy, dy, axx));
        float al  = __builtin_amdgcn_exp2f(sg);
        al = (al < ALPHA_MIN_F) ? 0.f : al;
        float w = T*al;
        cr += w*A1.z; cg += w*A1.w; cb += w*A2.x; T -= w;

        // register-only early break (local T bounds true T from above)
        if (__ballot(T > T_EPS) == 0ull) break;

        A0=B0; A1=B1; A2=B2; ra=rb;
        B0=C0; B1=C1; B2=C2; rb=rc;
    }
    #undef NEXT_ROW

    part[wv][tx] = make_float4(cr,cg,cb,T);
    __syncthreads();

    // Narrow in-block combine: wave 0, lane = pixel, fold 4 depth partials.
    if (wv == 0) {
        float R=0.f, G=0.f, B=0.f, Tt=1.f;
        #pragma unroll
        for (int s = 0; s < 4; ++s) {
            float4 v = part[s][tx];
            R += Tt*v.x; G += Tt*v.y; B += Tt*v.z; Tt *= v.w;
        }
        const int y = y0 + (tx >> 3);
        const int x = x0 + (tx & 7);
        float* o = out + (y*WW + x)*3;
        o[0] = R; o[1] = G; o[2] = B;
    }
}

extern "C" void kernel_launch(void* const* d_in, const int* in_sizes, int n_in,
                              void* d_out, int out_size, void* d_ws, size_t ws_size,
                              hipStream_t stream) {
    // d_in: 0=coords (unused by reference), 1=means, 2=quats, 3=scales, 4=opacities, 5=rgbs
    const float* means  = (const float*)d_in[1];
    const float* quats  = (const float*)d_in[2];
    const float* scales = (const float*)d_in[3];
    const float* opac   = (const float*)d_in[4];
    const float* rgbs   = (const float*)d_in[5];

    float* params = (float*)d_ws;                   // NROWS*PR floats = 36 KB

    gs_prep<<<3, 256, 0, stream>>>(means, quats, scales, opac, rgbs, params);
    gs_composite<<<1024, dim3(64,4), 0, stream>>>(params, (float*)d_out);
}

// Round 9
// 87.967 us; speedup vs baseline: 1.2954x; 1.2954x over previous
//
#include <hip/hip_runtime.h>
#include <math.h>

#define HH 256
#define WW 256
#define NG 714
#define NROWS 768          // padded rows; pad rows always culled
#define NGP4 716           // s_tz padded for float4 rank loop
#define SEG 23             // rows per wave sub-segment (32 segs x 23 = 736 >= 714)
#define NQTR 8             // depth slices per tile (8 x 4 waves = 32 segments)
#define FOCALF 128.0f
#define EPS2D_F 0.3f
#define ALPHA_MIN_F (1.0f/255.0f)
#define CAM_T_F 8.0f
#define LOG2E_F 1.4426950408889634f
#define PR 12              // floats/row: [mx,my,A2n,B2n][C2n,K,cr,cg][cb,e,f,thr]
#define T_EPS 0.003f       // in-wave early-break bound (error <= eps per channel)
#define NPX 65536

// Kernel 1: projection + conic + stable depth rank + scatter into sorted rows.
// Round-9: rank loop split 4-ways across a quad of lanes per row (45 iters
// each) + __shfl_xor integer reduce -- exact (sum of 0/1 ints), shortens the
// serial rank chain ~4x. Block = 1024 threads = 256 rows x 4 quad lanes.
// Conic stored NEGATED, prefolded with log2(e); K = log2(op) folded additively.
// Cull fields: e,f,thr as before (EXACT box cull).
__global__ __launch_bounds__(1024) void gs_prep(
    const float* __restrict__ means, const float* __restrict__ quats,
    const float* __restrict__ scales, const float* __restrict__ opacities,
    const float* __restrict__ rgbs, float* __restrict__ params)
{
    __shared__ float s_tz[NGP4];
    const int tid = threadIdx.x;            // 0..1023
    const int sub = tid & 3;                // quad lane (rank chunk)
    const int i   = blockIdx.x * 256 + (tid >> 2);   // row 0..767

    for (int j = tid; j < NGP4; j += 1024)
        s_tz[j] = (j < NG) ? (means[3*j+2] + CAM_T_F) : INFINITY;
    __syncthreads();

    if (i >= NG) {                      // pad rows: always culled (0 > thr=-1)
        if (sub == 0) {
            float4* row = (float4*)(params + i*PR);
            row[0] = make_float4(0.f,0.f,0.f,0.f);
            row[1] = make_float4(0.f,0.f,0.f,0.f);
            row[2] = make_float4(0.f,0.f,0.f,-1.f);
        }
        return;
    }

    const float tz = s_tz[i];

    // Partial rank over this lane's chunk of the 179 float4 groups.
    const float4* t4 = (const float4*)s_tz;
    int rank = 0;
    const int jj0 = sub * 45;
    const int jj1 = (sub == 3) ? 179 : (jj0 + 45);
    for (int jj = jj0; jj < jj1; ++jj) {
        float4 v = t4[jj];
        int j = 4*jj;
        rank += (v.x < tz) || (v.x == tz && (j+0) < i);
        rank += (v.y < tz) || (v.y == tz && (j+1) < i);
        rank += (v.z < tz) || (v.z == tz && (j+2) < i);
        rank += (v.w < tz) || (v.w == tz && (j+3) < i);
    }
    rank += __shfl_xor(rank, 1);
    rank += __shfl_xor(rank, 2);        // all 4 quad lanes now hold full rank
    if (sub != 0) return;

    float m0 = means[i*3+0], m1 = means[i*3+1];
    float qw = quats[i*4+0], qx = quats[i*4+1], qy = quats[i*4+2], qz = quats[i*4+3];
    float qn = rsqrtf(qw*qw + qx*qx + qy*qy + qz*qz);
    qw*=qn; qx*=qn; qy*=qn; qz*=qn;
    float sx = scales[i*3+0], sy = scales[i*3+1], sz = scales[i*3+2];
    float s0 = sx*sx, s1 = sy*sy, s2 = sz*sz;
    float R00 = 1.f-2.f*(qy*qy+qz*qz), R01 = 2.f*(qx*qy-qw*qz), R02 = 2.f*(qx*qz+qw*qy);
    float R10 = 2.f*(qx*qy+qw*qz),     R11 = 1.f-2.f*(qx*qx+qz*qz), R12 = 2.f*(qy*qz-qw*qx);
    float R20 = 2.f*(qx*qz-qw*qy),     R21 = 2.f*(qy*qz+qw*qx),     R22 = 1.f-2.f*(qx*qx+qy*qy);
    float S00 = R00*R00*s0 + R01*R01*s1 + R02*R02*s2;
    float S01 = R00*R10*s0 + R01*R11*s1 + R02*R12*s2;
    float S02 = R00*R20*s0 + R01*R21*s1 + R02*R22*s2;
    float S11 = R10*R10*s0 + R11*R11*s1 + R12*R12*s2;
    float S12 = R10*R20*s0 + R11*R21*s1 + R12*R22*s2;
    float S22 = R20*R20*s0 + R21*R21*s1 + R22*R22*s2;
    float inv = 1.f/tz;
    float mx = FOCALF*m0*inv + 0.5f*WW;
    float my = FOCALF*m1*inv + 0.5f*HH;
    float j0 = FOCALF*inv;
    float j2 = -FOCALF*m0*inv*inv;
    float j5 = -FOCALF*m1*inv*inv;
    float a = j0*j0*S00 + 2.f*j0*j2*S02 + j2*j2*S22 + EPS2D_F;
    float b = j0*(j0*S01 + j2*S12) + j5*(j0*S02 + j2*S22);
    float c = j0*j0*S11 + 2.f*j0*j5*S12 + j5*j5*S22 + EPS2D_F;
    float det = a*c - b*b;
    float idet = 1.f/det;
    float hA = 0.5f*c*idet*LOG2E_F;      // positive conic terms (log2-scaled)
    float Bc = -b*idet*LOG2E_F;
    float hC = 0.5f*a*idet*LOG2E_F;
    float e  = hC - Bc*Bc/(4.f*hA);      // min over dx of sigma' = e*dy^2
    float f  = hA - Bc*Bc/(4.f*hC);      // min over dy of sigma' = f*dx^2
    float op = 1.f/(1.f+__expf(-opacities[i]));
    float K  = log2f(op);                // folded into exponent
    float thr = log2f(255.f) + K;        // cull iff bound > thr
    float cr = 1.f/(1.f+__expf(-rgbs[i*3+0]));
    float cg = 1.f/(1.f+__expf(-rgbs[i*3+1]));
    float cb = 1.f/(1.f+__expf(-rgbs[i*3+2]));

    float4* row = (float4*)(params + rank*PR);
    row[0] = make_float4(mx, my, -hA, -Bc);
    row[1] = make_float4(-hC, K, cr, cg);
    row[2] = make_float4(cb, e, f, thr);
}

// Kernel 2: compositing, 2048 blocks = 256 tiles x 8 depth slices (round-6/8
// lessons: many small blocks, 16x16 tiles match gaussian footprint). Block =
// 4 waves = 4 sub-segments (23 rows). Per wave: ballot PRE-PASS then hit-only
// __ffsll loop with distance-2 register pipeline (round-5 win); register-only
// early break. Per-slice any-hit flag skips empty-slice stores (round-7 win).
// Round-9: __launch_bounds__(256, 8) -> all 8 blocks/CU co-resident (VGPR 20
// <= 64, LDS 8x16.1 KB <= 160 KB) so pre-pass L2 latency of the CU's whole
// block share overlaps instead of draining in 2 rounds.
__global__ __launch_bounds__(256, 8) void gs_composite(
    const float* __restrict__ params, float4* __restrict__ qpart,
    int* __restrict__ flags)
{
    __shared__ float4 part[4][4][64];       // [wave][row k][tx] = 16 KB
    __shared__ int s_any[4];
    const int tx = threadIdx.x;             // 0..63
    const int wv = __builtin_amdgcn_readfirstlane((int)threadIdx.y);
    const int tile = blockIdx.x >> 3;
    const int qtr  = blockIdx.x & 7;
    const int x0 = (tile & 15) * 16;
    const int y0 = (tile >> 4) * 16;
    const float px   = (float)(x0 + (tx & 15)) + 0.5f;
    const float yb   = (float)(y0 + ((tx >> 4) << 2)) + 0.5f;   // row-group base
    const float xc   = (float)x0 + 8.0f;    // box center, half-span 7.5
    const float ycen = (float)y0 + 8.0f;
    const int n0 = (qtr*4 + wv) * SEG;      // wave's sub-segment start

    const float4* p4 = (const float4*)params;

    // Pre-pass: lane l cull-tests row n0+l (exact same predicate as before).
    unsigned long long mask;
    {
        bool h = false;
        if (tx < SEG) {
            const int r = n0 + tx;
            float4 r0 = p4[3*r];
            float4 r2 = p4[3*r+2];
            float dymin = fmaxf(fabsf(ycen - r0.y) - 7.5f, 0.f);
            float dxmin = fmaxf(fabsf(xc   - r0.x) - 7.5f, 0.f);
            float mm = fmaxf(r2.y*dymin*dymin, r2.z*dxmin*dxmin);
            h = !(mm > r2.w);               // pads: 0 > -1 -> culled
        }
        mask = __ballot(h);                 // uniform across the wave
    }
    if (tx == 0) s_any[wv] = (mask != 0ull);

    float T0=1.f,r0=0.f,g0=0.f,bl0=0.f;
    float T1=1.f,r1=0.f,g1=0.f,bl1=0.f;
    float T2=1.f,r2=0.f,g2=0.f,bl2=0.f;
    float T3=1.f,r3=0.f,g3=0.f,bl3=0.f;

    // Hit-only main loop, distance-2 register pipeline through the mask.
    int ra = -1, rb = -1;
    float4 A0,A1,A2,B0,B1,B2;
    if (mask) { ra = n0 + (__ffsll(mask)-1); mask &= mask-1;
                A0=p4[3*ra]; A1=p4[3*ra+1]; A2=p4[3*ra+2]; }
    if (mask) { rb = n0 + (__ffsll(mask)-1); mask &= mask-1;
                B0=p4[3*rb]; B1=p4[3*rb+1]; B2=p4[3*rb+2]; }
    while (ra >= 0) {
        float4 C0,C1,C2; int rc = -1;
        if (mask) { rc = n0 + (__ffsll(mask)-1); mask &= mask-1;
                    C0=p4[3*rc]; C1=p4[3*rc+1]; C2=p4[3*rc+2]; }

        float dy0 = yb - A0.y;
        float dy1 = dy0 + 1.f, dy2 = dy0 + 2.f, dy3 = dy0 + 3.f;
        float dx  = px - A0.x;
        float axx = fmaf(A0.z*dx, dx, A1.y);    // A2n*dx^2 + K
        float bdx = A0.w*dx;

        float sg0 = fmaf(bdx, dy0, fmaf(A1.x*dy0, dy0, axx));
        float al0 = __builtin_amdgcn_exp2f(sg0);
        al0 = (al0 < ALPHA_MIN_F) ? 0.f : al0;
        float w0 = T0*al0; r0 += w0*A1.z; g0 += w0*A1.w; bl0 += w0*A2.x; T0 -= w0;

        float sg1 = fmaf(bdx, dy1, fmaf(A1.x*dy1, dy1, axx));
        float al1 = __builtin_amdgcn_exp2f(sg1);
        al1 = (al1 < ALPHA_MIN_F) ? 0.f : al1;
        float w1 = T1*al1; r1 += w1*A1.z; g1 += w1*A1.w; bl1 += w1*A2.x; T1 -= w1;

        float sg2 = fmaf(bdx, dy2, fmaf(A1.x*dy2, dy2, axx));
        float al2 = __builtin_amdgcn_exp2f(sg2);
        al2 = (al2 < ALPHA_MIN_F) ? 0.f : al2;
        float w2 = T2*al2; r2 += w2*A1.z; g2 += w2*A1.w; bl2 += w2*A2.x; T2 -= w2;

        float sg3 = fmaf(bdx, dy3, fmaf(A1.x*dy3, dy3, axx));
        float al3 = __builtin_amdgcn_exp2f(sg3);
        al3 = (al3 < ALPHA_MIN_F) ? 0.f : al3;
        float w3 = T3*al3; r3 += w3*A1.z; g3 += w3*A1.w; bl3 += w3*A2.x; T3 -= w3;

        // register-only early break (local T bounds true T from above)
        float tmax = fmaxf(fmaxf(T0,T1), fmaxf(T2,T3));
        if (__ballot(tmax > T_EPS) == 0ull) break;

        A0=B0; A1=B1; A2=B2; ra=rb;
        B0=C0; B1=C1; B2=C2; rb=rc;
    }

    part[wv][0][tx] = make_float4(r0,g0,bl0,T0);
    part[wv][1][tx] = make_float4(r1,g1,bl1,T1);
    part[wv][2][tx] = make_float4(r2,g2,bl2,T2);
    part[wv][3][tx] = make_float4(r3,g3,bl3,T3);
    __syncthreads();

    const int nz = s_any[0] | s_any[1] | s_any[2] | s_any[3];   // block-uniform
    if (wv == 0 && tx == 0) flags[blockIdx.x] = nz;             // poison-safe
    if (nz) {   // wave k reduces pixel-row k of each thread's bundle, in order
        const int k = wv;
        float R=0.f,G=0.f,B=0.f,T=1.f;
        #pragma unroll
        for (int s = 0; s < 4; ++s) {
            float4 v = part[s][k][tx];
            R += T*v.x; G += T*v.y; B += T*v.z; T *= v.w;
        }
        const int y = y0 + ((tx >> 4) << 2) + k;
        const int x = x0 + (tx & 15);
        qpart[qtr*NPX + y*WW + x] = make_float4(R,G,B,T);
    }
}

// Kernel 3: fold the flagged depth-slice partials in order. Block = tile so
// the slice-flag branches are block-uniform; empty slices are exact
// identities and are skipped (bit-identical result).
__global__ __launch_bounds__(256) void gs_combine(
    const int* __restrict__ flags, const float4* __restrict__ qpart,
    float* __restrict__ out)
{
    const int tile = blockIdx.x;
    const int t = threadIdx.x;              // 0..255 = pixel-in-tile
    const int x0 = (tile & 15) * 16;
    const int y0 = (tile >> 4) * 16;
    const int y = y0 + (t >> 4);
    const int x = x0 + (t & 15);
    const int px = y*WW + x;
    float R=0.f, G=0.f, B=0.f, T=1.f;
    #pragma unroll
    for (int q = 0; q < NQTR; ++q) {
        if (flags[tile*NQTR + q]) {         // block-uniform
            float4 p = qpart[q*NPX + px];
            R += T*p.x; G += T*p.y; B += T*p.z; T *= p.w;
        }
    }
    out[px*3+0] = R;
    out[px*3+1] = G;
    out[px*3+2] = B;
}

extern "C" void kernel_launch(void* const* d_in, const int* in_sizes, int n_in,
                              void* d_out, int out_size, void* d_ws, size_t ws_size,
                              hipStream_t stream) {
    // d_in: 0=coords (unused by reference), 1=means, 2=quats, 3=scales, 4=opacities, 5=rgbs
    const float* means  = (const float*)d_in[1];
    const float* quats  = (const float*)d_in[2];
    const float* scales = (const float*)d_in[3];
    const float* opac   = (const float*)d_in[4];
    const float* rgbs   = (const float*)d_in[5];

    char* ws = (char*)d_ws;
    float*  params = (float*)ws;                    // NROWS*PR floats = 36 KB
    int*    flags  = (int*)(ws + (40<<10));         // 2048 ints = 8 KB
    float4* qpart  = (float4*)(ws + (64<<10));      // 8*65536*16 B = 8 MB

    gs_prep<<<3, 1024, 0, stream>>>(means, quats, scales, opac, rgbs, params);
    gs_composite<<<256*NQTR, dim3(64,4), 0, stream>>>(params, qpart, flags);
    gs_combine<<<256, 256, 0, stream>>>(flags, qpart, (float*)d_out);
}